// Round 6
// baseline (372.418 us; speedup 1.0000x reference)
//
#include <hip/hip_runtime.h>
#include <hip/hip_bf16.h>
#include <stdint.h>

#define D_DIM 2048
#define N_STEPS 16384
#define B_BLK 1024
#define N_BLK (N_STEPS / B_BLK)       // 16
#define T_P (B_BLK / 128)             // 8 tiles per block dim
#define N_TILE (T_P * (T_P + 1) / 2)  // 36 lower tiles per block
#define ETA 0.01f
#define NWG 256
#define FLAG_STRIDE 16  // ints -> 64B per flag line
#define FLAG_INTS (NWG * FLAG_STRIDE + 16)
#define GD_INTS (8 * FLAG_STRIDE)  // per-XCD gram-done counters

typedef __attribute__((ext_vector_type(8))) short short8_t;
typedef __attribute__((ext_vector_type(4))) float floatx4;

__device__ __forceinline__ short f2bf(float f) {
  __hip_bfloat16 h = __float2bfloat16(f);
  return __builtin_bit_cast(short, h);
}
__device__ __forceinline__ float bf2f(uint32_t bits) {
  return __builtin_bit_cast(float, bits << 16);
}

// Write-through store (relaxed agent atomic). R4 lesson: ONLY for KB-scale
// sync payloads. Bulk write-through of xb (64MB) -> 694us disaster.
__device__ __forceinline__ void store_wt(float* p, float v) {
  __hip_atomic_store(p, v, __ATOMIC_RELAXED, __HIP_MEMORY_SCOPE_AGENT);
}

// Async global->LDS, 16B per lane (lane-linear LDS dest).
__device__ __forceinline__ void gl_lds16(const short* g, short* l) {
  __builtin_amdgcn_global_load_lds(
      (const __attribute__((address_space(1))) void*)g,
      (__attribute__((address_space(3))) void*)l, 16, 0, 0);
}

// ---------------------------------------------------------------------------
// Phase 0: cast xs -> xb (normal cached stores); WG0 inits flags + gram-done
// counters and copies theta slot 0. (R3 version, proven.)
// ---------------------------------------------------------------------------
__global__ __launch_bounds__(256) void cast_kernel(
    const float* __restrict__ xs, short* __restrict__ xb,
    const float* __restrict__ theta_in, float* __restrict__ theta_arr,
    int* __restrict__ flags) {
  size_t i = (size_t)blockIdx.x * 256 + threadIdx.x;
  float4 a = ((const float4*)xs)[i * 2];
  float4 b = ((const float4*)xs)[i * 2 + 1];
  short8_t v;
  v[0] = f2bf(a.x); v[1] = f2bf(a.y); v[2] = f2bf(a.z); v[3] = f2bf(a.w);
  v[4] = f2bf(b.x); v[5] = f2bf(b.y); v[6] = f2bf(b.z); v[7] = f2bf(b.w);
  *(short8_t*)(xb + i * 8) = v;

  if (blockIdx.x == 0) {
    int tid = threadIdx.x;
    for (int k = tid; k < FLAG_INTS + GD_INTS; k += 256) flags[k] = 0;
    float4 t0 = ((const float4*)theta_in)[tid * 2];
    float4 t1 = ((const float4*)theta_in)[tid * 2 + 1];
    ((float4*)theta_arr)[tid * 2] = t0;
    ((float4*)theta_arr)[tid * 2 + 1] = t1;
  }
}

// ---------------------------------------------------------------------------
// Phase 1: block-local Gram tiles, XCD-locality dispatch swizzle.
// R6: intra-XCD block SEQUENCING gate. XCD x owns blocks {x, x+8}; with all
// 72 WGs co-resident the live panel set is 8MB vs the 4MB XCD L2 -> panel
// re-reads (9x reuse) thrash to MALL. Block x+8's tiles now sleep-poll a
// per-XCD done counter until block x's 36 tiles complete, halving the live
// set to exactly L2 size. PURE PERFORMANCE HINT: xb comes from the previous
// kernel, so a gate misfire (guard timeout) only loses locality, never
// correctness. Dispatch order: j<36 WGs have lower blockIdx -> launch first.
// ---------------------------------------------------------------------------
__global__ __launch_bounds__(256) void gram_kernel(const short* __restrict__ xb,
                                                   short* __restrict__ G,
                                                   int* __restrict__ gramdone) {
  int i = blockIdx.x;
  int x = i & 7, j = i >> 3;  // x: XCD slot, j: 0..71
  int b = (j < 36) ? x : x + 8;
  int t = (j < 36) ? j : j - 36;
  int ti = 0;
  while ((ti + 1) * (ti + 2) / 2 <= t) ti++;
  int tj = t - ti * (ti + 1) / 2;

  __shared__ short As[128 * 64];
  __shared__ short Bs[128 * 64];

  int tid = threadIdx.x;
  int* gd = gramdone + x * FLAG_STRIDE;

  if (j >= 36) {  // second block: wait for first block's tiles (perf gate)
    if (tid == 0) {
      int guard = 0;
      while (__hip_atomic_load(gd, __ATOMIC_RELAXED,
                               __HIP_MEMORY_SCOPE_AGENT) < N_TILE &&
             guard < (1 << 12)) {
        guard++;
        __builtin_amdgcn_s_sleep(8);
      }
    }
    __syncthreads();
  }

  int lane = tid & 63;
  int w = tid >> 6;
  int wm = w >> 1, wn = w & 1;
  int quad = lane >> 4, rr = lane & 15;

  floatx4 acc[4][4];
#pragma unroll
  for (int ii = 0; ii < 4; ii++)
#pragma unroll
    for (int jj = 0; jj < 4; jj++)
#pragma unroll
      for (int r = 0; r < 4; r++) acc[ii][jj][r] = 0.f;

  const short* Arow = xb + (size_t)(b * B_BLK + ti * 128) * D_DIM;
  const short* Brow = xb + (size_t)(b * B_BLK + tj * 128) * D_DIM;
  bool diag = (ti == tj);

  for (int kk = 0; kk < D_DIM; kk += 64) {
#pragma unroll
    for (int tch = 0; tch < 4; tch++) {
      int chunk = tch * 256 + tid;  // 1024 x 16B chunks = 128x64 bf16
      int row = chunk >> 3, slot = chunk & 7;
      int cc = slot ^ (row & 7);  // swizzle
      gl_lds16(Arow + (size_t)row * D_DIM + kk + cc * 8, &As[chunk * 8]);
      if (!diag)
        gl_lds16(Brow + (size_t)row * D_DIM + kk + cc * 8, &Bs[chunk * 8]);
    }
    __syncthreads();  // drains vmcnt -> LDS staging complete

    const short* Bsrc = diag ? As : Bs;
#pragma unroll
    for (int ks = 0; ks < 2; ks++) {  // k-offsets 0, 32
      short8_t af[4], bfr[4];
#pragma unroll
      for (int mt = 0; mt < 4; mt++) {
        int r = wm * 64 + mt * 16 + rr;
        int slot = (ks * 4 + quad) ^ (r & 7);
        af[mt] = *(const short8_t*)(&As[r * 64 + slot * 8]);
      }
#pragma unroll
      for (int nt = 0; nt < 4; nt++) {
        int r = wn * 64 + nt * 16 + rr;
        int slot = (ks * 4 + quad) ^ (r & 7);
        bfr[nt] = *(const short8_t*)(&Bsrc[r * 64 + slot * 8]);
      }
#pragma unroll
      for (int mt = 0; mt < 4; mt++)
#pragma unroll
        for (int nt = 0; nt < 4; nt++)
          acc[mt][nt] = __builtin_amdgcn_mfma_f32_16x16x32_bf16(
              af[mt], bfr[nt], acc[mt][nt], 0, 0, 0);
    }
    __syncthreads();
  }

  // C/D layout: col=lane&15, row=(lane>>4)*4+reg  [verified m89/m91]
  size_t gbase = ((size_t)(b * N_TILE + t)) * (128 * 128);
  int col0 = lane & 15;
  int row0 = (lane >> 4) * 4;
#pragma unroll
  for (int mt = 0; mt < 4; mt++)
#pragma unroll
    for (int nt = 0; nt < 4; nt++)
#pragma unroll
      for (int r = 0; r < 4; r++) {
        int row = wm * 64 + mt * 16 + row0 + r;
        int col = wn * 64 + nt * 16 + col0;
        G[gbase + (size_t)row * 128 + col] = f2bf(acc[mt][nt][r]);
      }

  if (j < 36 && tid == 0)  // signal first-block tile completion (perf hint)
    __hip_atomic_fetch_add(gd, 1, __ATOMIC_RELAXED, __HIP_MEMORY_SCOPE_AGENT);
}

// ---------------------------------------------------------------------------
// Split all-to-all grid barrier (flush-free, relaxed agent atomics). Proven
// transport (R1/R3): cached post-barrier loads, prefetches hidden in the
// arrive->wait window.
// ---------------------------------------------------------------------------
__device__ __forceinline__ void bar_arrive(int* flags, int wg, int tid,
                                           int gen) {
  __syncthreads();  // all waves' stores drained (vmcnt 0) before flag post
  if (tid == 0)
    __hip_atomic_store(&flags[wg * FLAG_STRIDE], gen, __ATOMIC_RELAXED,
                       __HIP_MEMORY_SCOPE_AGENT);
}

__device__ __forceinline__ void bar_wait(int* flags, int tid, int gen) {
  int guard = 0;
  while (__hip_atomic_load(&flags[tid * FLAG_STRIDE], __ATOMIC_RELAXED,
                           __HIP_MEMORY_SCOPE_AGENT) < gen &&
         guard < (1 << 20)) {
    guard++;
    __builtin_amdgcn_s_sleep(1);
  }
  asm volatile("" ::: "memory");
  __syncthreads();
}

__device__ __forceinline__ float wave_reduce(float s) {
  for (int off = 32; off; off >>= 1) s += __shfl_xor(s, off, 64);
  return s;
}

// ---------------------------------------------------------------------------
// Phase 2: R3 structure, SINGLE dispatch (R5's 4-way diagnostic split cost
// ~2.3us and its purpose is served). Final block writes d_out directly.
// ---------------------------------------------------------------------------
__global__ __launch_bounds__(256, 1) void solve_kernel(
    const short* __restrict__ xb, const short* __restrict__ G,
    float* __restrict__ theta_arr, float* __restrict__ c0_arr,
    float* __restrict__ c1_arr, int* flags, float* __restrict__ d_out) {
  int tid = threadIdx.x;
  int wg = blockIdx.x;
  int lane = tid & 63;
  int wid = tid >> 6;
  int gw = wg * 4 + wid;       // 0..1023: row handled in phases A/S
  int ti = gw >> 7, kr = gw & 127;
  int oct = (wg & 7) * 32 + (wg >> 3);  // phase C d-octet (XCD line sharing)
  int d0 = oct * 8;
  int gen = 0;

  __shared__ float redc[4][8];

  // Register prefetch state (static addresses: xb, G are const during solve)
  short8_t xa[4];   // phase A: my row, 4x 8-bf16 chunks
  uint32_t gv[8];   // phase S: my G row segments (2 bf16 per lane per tile)
  short8_t xc[4];   // phase C: 4 rows x my 8-dim slice

  // ---- prefetch for block 0
  {
    const short* xr = xb + (size_t)gw * D_DIM;
#pragma unroll
    for (int i = 0; i < 4; i++)
      xa[i] = *(const short8_t*)(xr + (i * 64 + lane) * 8);
#pragma unroll
    for (int tj = 0; tj < T_P; tj++)
      if (tj <= ti) {
        size_t base = ((size_t)(ti * (ti + 1) / 2 + tj)) * (128 * 128) +
                      (size_t)kr * 128;
        gv[tj] = *(const uint32_t*)(G + base + lane * 2);
      }
  }

  for (int b = 0; b < N_BLK; b++) {
    const float* theta = theta_arr + (size_t)b * D_DIM;  // rotated slots
    float* c0 = c0_arr + (size_t)b * B_BLK;
    float* c1 = c1_arr + (size_t)b * B_BLK;
    float p_k;
    float th8 = 0.f;

    // ---- Phase A: p_k = <x_gw, theta_b>; c0 = ETA/(1+exp(p))
    {
      if (tid < 8) th8 = theta[d0 + tid];  // phase C theta slice, issued early
      float s = 0.f;
#pragma unroll
      for (int i = 0; i < 4; i++) {
        int idx = (i * 64 + lane) * 8;
        float4 t0 = *(const float4*)(theta + idx);
        float4 t1 = *(const float4*)(theta + idx + 4);
        short8_t xv = xa[i];
        s += bf2f((uint16_t)xv[0]) * t0.x + bf2f((uint16_t)xv[1]) * t0.y +
             bf2f((uint16_t)xv[2]) * t0.z + bf2f((uint16_t)xv[3]) * t0.w +
             bf2f((uint16_t)xv[4]) * t1.x + bf2f((uint16_t)xv[5]) * t1.y +
             bf2f((uint16_t)xv[6]) * t1.z + bf2f((uint16_t)xv[7]) * t1.w;
      }
      s = wave_reduce(s);
      p_k = s;
      if (lane == 0) store_wt(&c0[gw], ETA / (1.f + __expf(s)));
    }
    bar_arrive(flags, wg, tid, ++gen);
    {  // prefetch phase C x slices for THIS block (hidden under barrier 1)
      const short* xp = xb + ((size_t)b * B_BLK + tid * 4) * D_DIM + d0;
#pragma unroll
      for (int j = 0; j < 4; j++)
        xc[j] = *(const short8_t*)(xp + (size_t)j * D_DIM);
    }
    bar_wait(flags, tid, gen);

    // ---- Phase S: c1[k] = ETA/(1+exp(p_k + tril(G_b)[k,:] . c0))
    {
      float2 cv[T_P];
#pragma unroll
      for (int tj = 0; tj < T_P; tj++)  // all dynamic loads issue together
        if (tj <= ti) cv[tj] = *(const float2*)(c0 + tj * 128 + lane * 2);
      float s = 0.f;
      int jc = lane * 2;
#pragma unroll
      for (int tj = 0; tj < T_P; tj++)
        if (tj <= ti) {
          int lim = (tj == ti) ? kr : 128;
          if (jc < lim) s += bf2f(gv[tj] & 0xffffu) * cv[tj].x;
          if (jc + 1 < lim) s += bf2f(gv[tj] >> 16) * cv[tj].y;
        }
      s = wave_reduce(s);
      if (lane == 0) store_wt(&c1[gw], ETA / (1.f + __expf(p_k + s)));
    }
    bar_arrive(flags, wg, tid, ++gen);
    if (b + 1 < N_BLK) {  // prefetch next block's phase A row
      const short* xr = xb + (size_t)((b + 1) * B_BLK + gw) * D_DIM;
#pragma unroll
      for (int i = 0; i < 4; i++)
        xa[i] = *(const short8_t*)(xr + (i * 64 + lane) * 8);
    }
    bar_wait(flags, tid, gen);

    // ---- Phase C: theta_{b+1}[d] = theta_b[d] + sum_k c1[k] xb[k][d]
    // All 256 WGs; WG owns dims [d0, d0+8); thread owns rows [4*tid, 4*tid+4).
    {
      float4 c1v = *(const float4*)(c1 + tid * 4);  // only dynamic load
      float a8[8];
#pragma unroll
      for (int jj = 0; jj < 8; jj++) a8[jj] = 0.f;
#pragma unroll
      for (int j = 0; j < 4; j++) {
        float c = (&c1v.x)[j];
        short8_t xv = xc[j];
#pragma unroll
        for (int jj = 0; jj < 8; jj++) a8[jj] += c * bf2f((uint16_t)xv[jj]);
      }
#pragma unroll
      for (int off = 32; off; off >>= 1)
#pragma unroll
        for (int jj = 0; jj < 8; jj++) a8[jj] += __shfl_xor(a8[jj], off, 64);
      if (lane == 0) {
#pragma unroll
        for (int jj = 0; jj < 8; jj++) redc[wid][jj] = a8[jj];
      }
      __syncthreads();
      if (tid < 8) {
        float tot =
            redc[0][tid] + redc[1][tid] + redc[2][tid] + redc[3][tid];
        // final block writes the kernel output directly (no trailing memcpy)
        float* dst = (b + 1 < N_BLK)
                         ? &theta_arr[(size_t)(b + 1) * D_DIM + d0 + tid]
                         : &d_out[d0 + tid];
        store_wt(dst, th8 + tot);
      }
    }
    if (b + 1 < N_BLK) {
      bar_arrive(flags, wg, tid, ++gen);
      {  // prefetch next block's G segments (hidden under barrier 3)
        size_t base =
            ((size_t)((b + 1) * N_TILE + ti * (ti + 1) / 2)) * (128 * 128) +
            (size_t)kr * 128;
#pragma unroll
        for (int tj = 0; tj < T_P; tj++)
          if (tj <= ti)
            gv[tj] = *(const uint32_t*)(G + base + (size_t)tj * (128 * 128) +
                                        lane * 2);
      }
      bar_wait(flags, tid, gen);
    }
  }
}

// ---------------------------------------------------------------------------
// R6 stream: cast, gram (gated), solve (single). Budget model (from R5's fill
// discovery): ~158us harness poison-fill is inside the timed region and
// un-actionable; actionable kernels = cast ~32 + gram ~45 + solve ~111.5.
// ---------------------------------------------------------------------------
extern "C" void kernel_launch(void* const* d_in, const int* in_sizes, int n_in,
                              void* d_out, int out_size, void* d_ws,
                              size_t ws_size, hipStream_t stream) {
  const float* theta_in = (const float*)d_in[0];  // (2048,)
  const float* xs = (const float*)d_in[1];        // (16384, 2048) fp32

  char* ws = (char*)d_ws;
  const size_t XB_BYTES = (size_t)N_STEPS * D_DIM * sizeof(short);  // 64MB
  const size_t G_BYTES = (size_t)N_BLK * N_TILE * 128 * 128 * sizeof(short);
  short* xb = (short*)ws;
  short* G = (short*)(ws + XB_BYTES);
  float* theta_arr = (float*)(ws + XB_BYTES + G_BYTES);  // (N_BLK+1) x 2048
  float* c0_arr = theta_arr + (size_t)(N_BLK + 1) * D_DIM;
  float* c1_arr = c0_arr + (size_t)N_BLK * B_BLK;
  int* flags = (int*)(c1_arr + (size_t)N_BLK * B_BLK);
  int* gramdone = flags + FLAG_INTS;

  cast_kernel<<<(N_STEPS * D_DIM / 8) / 256, 256, 0, stream>>>(
      xs, xb, theta_in, theta_arr, flags);
  gram_kernel<<<N_BLK * N_TILE, 256, 0, stream>>>(xb, G, gramdone);
  solve_kernel<<<NWG, 256, 0, stream>>>(xb, G, theta_arr, c0_arr, c1_arr,
                                        flags, (float*)d_out);
}

// Round 7
// 349.980 us; speedup vs baseline: 1.0641x; 1.0641x over previous
//
#include <hip/hip_runtime.h>
#include <hip/hip_bf16.h>
#include <stdint.h>

#define D_DIM 2048
#define N_STEPS 16384
#define B_BLK 1024
#define N_BLK (N_STEPS / B_BLK)       // 16
#define T_P (B_BLK / 128)             // 8 tiles per block dim
#define N_TILE (T_P * (T_P + 1) / 2)  // 36 lower tiles per block
#define ETA 0.01f
#define NWG 256
#define FLAG_STRIDE 16  // ints -> 64B per flag line
#define FLAG_INTS (NWG * FLAG_STRIDE + 16)

typedef __attribute__((ext_vector_type(8))) short short8_t;
typedef __attribute__((ext_vector_type(4))) float floatx4;

__device__ __forceinline__ short f2bf(float f) {
  __hip_bfloat16 h = __float2bfloat16(f);
  return __builtin_bit_cast(short, h);
}
__device__ __forceinline__ float bf2f(uint32_t bits) {
  return __builtin_bit_cast(float, bits << 16);
}

// Write-through store (relaxed agent atomic). ONLY for KB-scale sync
// payloads (R4 lesson: bulk write-through evicts the cache hierarchy).
__device__ __forceinline__ void store_wt(float* p, float v) {
  __hip_atomic_store(p, v, __ATOMIC_RELAXED, __HIP_MEMORY_SCOPE_AGENT);
}

// Async global->LDS, 16B per lane (lane-linear LDS dest).
__device__ __forceinline__ void gl_lds16(const short* g, short* l) {
  __builtin_amdgcn_global_load_lds(
      (const __attribute__((address_space(1))) void*)g,
      (__attribute__((address_space(3))) void*)l, 16, 0, 0);
}

// ---------------------------------------------------------------------------
// Phase 0: cast xs -> xb; WG0 inits flags and copies theta slot 0.
// (R3 exact, measured-best.)
// ---------------------------------------------------------------------------
__global__ __launch_bounds__(256) void cast_kernel(
    const float* __restrict__ xs, short* __restrict__ xb,
    const float* __restrict__ theta_in, float* __restrict__ theta_arr,
    int* __restrict__ flags) {
  size_t i = (size_t)blockIdx.x * 256 + threadIdx.x;
  float4 a = ((const float4*)xs)[i * 2];
  float4 b = ((const float4*)xs)[i * 2 + 1];
  short8_t v;
  v[0] = f2bf(a.x); v[1] = f2bf(a.y); v[2] = f2bf(a.z); v[3] = f2bf(a.w);
  v[4] = f2bf(b.x); v[5] = f2bf(b.y); v[6] = f2bf(b.z); v[7] = f2bf(b.w);
  *(short8_t*)(xb + i * 8) = v;

  if (blockIdx.x == 0) {
    int tid = threadIdx.x;
    for (int k = tid; k < FLAG_INTS; k += 256) flags[k] = 0;
    float4 t0 = ((const float4*)theta_in)[tid * 2];
    float4 t1 = ((const float4*)theta_in)[tid * 2 + 1];
    ((float4*)theta_arr)[tid * 2] = t0;
    ((float4*)theta_arr)[tid * 2 + 1] = t1;
  }
}

// ---------------------------------------------------------------------------
// Phase 1: block-local Gram tiles, XCD-locality dispatch swizzle (R3 exact).
// R6 lesson: do NOT gate/sequence the two blocks per XCD — gram is
// latency/occupancy-bound; halving active WGs cost +19us, locality gained
// nothing. 72 co-resident WGs per XCD is the right operating point.
// ---------------------------------------------------------------------------
__global__ __launch_bounds__(256) void gram_kernel(const short* __restrict__ xb,
                                                   short* __restrict__ G) {
  int i = blockIdx.x;
  int x = i & 7, j = i >> 3;  // x: XCD slot, j: 0..71
  int b = (j < 36) ? x : x + 8;
  int t = (j < 36) ? j : j - 36;
  int ti = 0;
  while ((ti + 1) * (ti + 2) / 2 <= t) ti++;
  int tj = t - ti * (ti + 1) / 2;

  __shared__ short As[128 * 64];
  __shared__ short Bs[128 * 64];

  int tid = threadIdx.x;
  int lane = tid & 63;
  int w = tid >> 6;
  int wm = w >> 1, wn = w & 1;
  int quad = lane >> 4, rr = lane & 15;

  floatx4 acc[4][4];
#pragma unroll
  for (int ii = 0; ii < 4; ii++)
#pragma unroll
    for (int jj = 0; jj < 4; jj++)
#pragma unroll
      for (int r = 0; r < 4; r++) acc[ii][jj][r] = 0.f;

  const short* Arow = xb + (size_t)(b * B_BLK + ti * 128) * D_DIM;
  const short* Brow = xb + (size_t)(b * B_BLK + tj * 128) * D_DIM;
  bool diag = (ti == tj);

  for (int kk = 0; kk < D_DIM; kk += 64) {
#pragma unroll
    for (int tch = 0; tch < 4; tch++) {
      int chunk = tch * 256 + tid;  // 1024 x 16B chunks = 128x64 bf16
      int row = chunk >> 3, slot = chunk & 7;
      int cc = slot ^ (row & 7);  // swizzle
      gl_lds16(Arow + (size_t)row * D_DIM + kk + cc * 8, &As[chunk * 8]);
      if (!diag)
        gl_lds16(Brow + (size_t)row * D_DIM + kk + cc * 8, &Bs[chunk * 8]);
    }
    __syncthreads();  // drains vmcnt -> LDS staging complete

    const short* Bsrc = diag ? As : Bs;
#pragma unroll
    for (int ks = 0; ks < 2; ks++) {  // k-offsets 0, 32
      short8_t af[4], bfr[4];
#pragma unroll
      for (int mt = 0; mt < 4; mt++) {
        int r = wm * 64 + mt * 16 + rr;
        int slot = (ks * 4 + quad) ^ (r & 7);
        af[mt] = *(const short8_t*)(&As[r * 64 + slot * 8]);
      }
#pragma unroll
      for (int nt = 0; nt < 4; nt++) {
        int r = wn * 64 + nt * 16 + rr;
        int slot = (ks * 4 + quad) ^ (r & 7);
        bfr[nt] = *(const short8_t*)(&Bsrc[r * 64 + slot * 8]);
      }
#pragma unroll
      for (int mt = 0; mt < 4; mt++)
#pragma unroll
        for (int nt = 0; nt < 4; nt++)
          acc[mt][nt] = __builtin_amdgcn_mfma_f32_16x16x32_bf16(
              af[mt], bfr[nt], acc[mt][nt], 0, 0, 0);
    }
    __syncthreads();
  }

  // C/D layout: col=lane&15, row=(lane>>4)*4+reg  [verified m89/m91]
  size_t gbase = ((size_t)(b * N_TILE + t)) * (128 * 128);
  int col0 = lane & 15;
  int row0 = (lane >> 4) * 4;
#pragma unroll
  for (int mt = 0; mt < 4; mt++)
#pragma unroll
    for (int nt = 0; nt < 4; nt++)
#pragma unroll
      for (int r = 0; r < 4; r++) {
        int row = wm * 64 + mt * 16 + row0 + r;
        int col = wn * 64 + nt * 16 + col0;
        G[gbase + (size_t)row * 128 + col] = f2bf(acc[mt][nt][r]);
      }
}

// ---------------------------------------------------------------------------
// Split all-to-all grid barrier (flush-free, relaxed agent atomics). Proven
// transport (R1/R3): cached post-barrier loads, prefetches hidden in the
// arrive->wait window. (R2 lesson: payload-polling is slower.)
// ---------------------------------------------------------------------------
__device__ __forceinline__ void bar_arrive(int* flags, int wg, int tid,
                                           int gen) {
  __syncthreads();  // all waves' stores drained (vmcnt 0) before flag post
  if (tid == 0)
    __hip_atomic_store(&flags[wg * FLAG_STRIDE], gen, __ATOMIC_RELAXED,
                       __HIP_MEMORY_SCOPE_AGENT);
}

__device__ __forceinline__ void bar_wait(int* flags, int tid, int gen) {
  int guard = 0;
  while (__hip_atomic_load(&flags[tid * FLAG_STRIDE], __ATOMIC_RELAXED,
                           __HIP_MEMORY_SCOPE_AGENT) < gen &&
         guard < (1 << 20)) {
    guard++;
    __builtin_amdgcn_s_sleep(1);
  }
  asm volatile("" ::: "memory");
  __syncthreads();
}

__device__ __forceinline__ float wave_reduce(float s) {
  for (int off = 32; off; off >>= 1) s += __shfl_xor(s, off, 64);
  return s;
}

// ---------------------------------------------------------------------------
// Phase 2: R3 exact. Latency-pipelined: all static-address data (xb rows for
// A/C, G segments for S) register-prefetched inside the barrier windows; each
// phase pays ONE dynamic-load round trip (theta / c0 / c1). Final block
// writes d_out directly.
// ---------------------------------------------------------------------------
__global__ __launch_bounds__(256, 1) void solve_kernel(
    const short* __restrict__ xb, const short* __restrict__ G,
    float* __restrict__ theta_arr, float* __restrict__ c0_arr,
    float* __restrict__ c1_arr, int* flags, float* __restrict__ d_out) {
  int tid = threadIdx.x;
  int wg = blockIdx.x;
  int lane = tid & 63;
  int wid = tid >> 6;
  int gw = wg * 4 + wid;       // 0..1023: row handled in phases A/S
  int ti = gw >> 7, kr = gw & 127;
  int oct = (wg & 7) * 32 + (wg >> 3);  // phase C d-octet (XCD line sharing)
  int d0 = oct * 8;
  int gen = 0;

  __shared__ float redc[4][8];

  // Register prefetch state (static addresses: xb, G are const during solve)
  short8_t xa[4];   // phase A: my row, 4x 8-bf16 chunks
  uint32_t gv[8];   // phase S: my G row segments (2 bf16 per lane per tile)
  short8_t xc[4];   // phase C: 4 rows x my 8-dim slice

  // ---- prefetch for block 0
  {
    const short* xr = xb + (size_t)gw * D_DIM;
#pragma unroll
    for (int i = 0; i < 4; i++)
      xa[i] = *(const short8_t*)(xr + (i * 64 + lane) * 8);
#pragma unroll
    for (int tj = 0; tj < T_P; tj++)
      if (tj <= ti) {
        size_t base = ((size_t)(ti * (ti + 1) / 2 + tj)) * (128 * 128) +
                      (size_t)kr * 128;
        gv[tj] = *(const uint32_t*)(G + base + lane * 2);
      }
  }

  for (int b = 0; b < N_BLK; b++) {
    const float* theta = theta_arr + (size_t)b * D_DIM;  // rotated slots
    float* c0 = c0_arr + (size_t)b * B_BLK;
    float* c1 = c1_arr + (size_t)b * B_BLK;
    float p_k;
    float th8 = 0.f;

    // ---- Phase A: p_k = <x_gw, theta_b>; c0 = ETA/(1+exp(p))
    {
      if (tid < 8) th8 = theta[d0 + tid];  // phase C theta slice, issued early
      float s = 0.f;
#pragma unroll
      for (int i = 0; i < 4; i++) {
        int idx = (i * 64 + lane) * 8;
        float4 t0 = *(const float4*)(theta + idx);
        float4 t1 = *(const float4*)(theta + idx + 4);
        short8_t xv = xa[i];
        s += bf2f((uint16_t)xv[0]) * t0.x + bf2f((uint16_t)xv[1]) * t0.y +
             bf2f((uint16_t)xv[2]) * t0.z + bf2f((uint16_t)xv[3]) * t0.w +
             bf2f((uint16_t)xv[4]) * t1.x + bf2f((uint16_t)xv[5]) * t1.y +
             bf2f((uint16_t)xv[6]) * t1.z + bf2f((uint16_t)xv[7]) * t1.w;
      }
      s = wave_reduce(s);
      p_k = s;
      if (lane == 0) store_wt(&c0[gw], ETA / (1.f + __expf(s)));
    }
    bar_arrive(flags, wg, tid, ++gen);
    {  // prefetch phase C x slices for THIS block (hidden under barrier 1)
      const short* xp = xb + ((size_t)b * B_BLK + tid * 4) * D_DIM + d0;
#pragma unroll
      for (int j = 0; j < 4; j++)
        xc[j] = *(const short8_t*)(xp + (size_t)j * D_DIM);
    }
    bar_wait(flags, tid, gen);

    // ---- Phase S: c1[k] = ETA/(1+exp(p_k + tril(G_b)[k,:] . c0))
    {
      float2 cv[T_P];
#pragma unroll
      for (int tj = 0; tj < T_P; tj++)  // all dynamic loads issue together
        if (tj <= ti) cv[tj] = *(const float2*)(c0 + tj * 128 + lane * 2);
      float s = 0.f;
      int jc = lane * 2;
#pragma unroll
      for (int tj = 0; tj < T_P; tj++)
        if (tj <= ti) {
          int lim = (tj == ti) ? kr : 128;
          if (jc < lim) s += bf2f(gv[tj] & 0xffffu) * cv[tj].x;
          if (jc + 1 < lim) s += bf2f(gv[tj] >> 16) * cv[tj].y;
        }
      s = wave_reduce(s);
      if (lane == 0) store_wt(&c1[gw], ETA / (1.f + __expf(p_k + s)));
    }
    bar_arrive(flags, wg, tid, ++gen);
    if (b + 1 < N_BLK) {  // prefetch next block's phase A row
      const short* xr = xb + (size_t)((b + 1) * B_BLK + gw) * D_DIM;
#pragma unroll
      for (int i = 0; i < 4; i++)
        xa[i] = *(const short8_t*)(xr + (i * 64 + lane) * 8);
    }
    bar_wait(flags, tid, gen);

    // ---- Phase C: theta_{b+1}[d] = theta_b[d] + sum_k c1[k] xb[k][d]
    // All 256 WGs; WG owns dims [d0, d0+8); thread owns rows [4*tid, 4*tid+4).
    {
      float4 c1v = *(const float4*)(c1 + tid * 4);  // only dynamic load
      float a8[8];
#pragma unroll
      for (int jj = 0; jj < 8; jj++) a8[jj] = 0.f;
#pragma unroll
      for (int j = 0; j < 4; j++) {
        float c = (&c1v.x)[j];
        short8_t xv = xc[j];
#pragma unroll
        for (int jj = 0; jj < 8; jj++) a8[jj] += c * bf2f((uint16_t)xv[jj]);
      }
#pragma unroll
      for (int off = 32; off; off >>= 1)
#pragma unroll
        for (int jj = 0; jj < 8; jj++) a8[jj] += __shfl_xor(a8[jj], off, 64);
      if (lane == 0) {
#pragma unroll
        for (int jj = 0; jj < 8; jj++) redc[wid][jj] = a8[jj];
      }
      __syncthreads();
      if (tid < 8) {
        float tot =
            redc[0][tid] + redc[1][tid] + redc[2][tid] + redc[3][tid];
        // final block writes the kernel output directly (no trailing memcpy)
        float* dst = (b + 1 < N_BLK)
                         ? &theta_arr[(size_t)(b + 1) * D_DIM + d0 + tid]
                         : &d_out[d0 + tid];
        store_wt(dst, th8 + tot);
      }
    }
    if (b + 1 < N_BLK) {
      bar_arrive(flags, wg, tid, ++gen);
      {  // prefetch next block's G segments (hidden under barrier 3)
        size_t base =
            ((size_t)((b + 1) * N_TILE + ti * (ti + 1) / 2)) * (128 * 128) +
            (size_t)kr * 128;
#pragma unroll
        for (int tj = 0; tj < T_P; tj++)
          if (tj <= ti)
            gv[tj] = *(const uint32_t*)(G + base + (size_t)tj * (128 * 128) +
                                        lane * 2);
      }
      bar_wait(flags, tid, gen);
    }
  }
}

// ---------------------------------------------------------------------------
// R7: exact R3 stream (measured-best 351.5us). Budget model: ~158us harness
// poison-fill (un-actionable) + cast ~31 (BW floor) + gram ~45-50 (m97-
// structure ceiling at this grid) + solve ~111-117 (48 serial cross-XCD sync
// hops, structural).
// ---------------------------------------------------------------------------
extern "C" void kernel_launch(void* const* d_in, const int* in_sizes, int n_in,
                              void* d_out, int out_size, void* d_ws,
                              size_t ws_size, hipStream_t stream) {
  const float* theta_in = (const float*)d_in[0];  // (2048,)
  const float* xs = (const float*)d_in[1];        // (16384, 2048) fp32

  char* ws = (char*)d_ws;
  const size_t XB_BYTES = (size_t)N_STEPS * D_DIM * sizeof(short);  // 64MB
  const size_t G_BYTES = (size_t)N_BLK * N_TILE * 128 * 128 * sizeof(short);
  short* xb = (short*)ws;
  short* G = (short*)(ws + XB_BYTES);
  float* theta_arr = (float*)(ws + XB_BYTES + G_BYTES);  // (N_BLK+1) x 2048
  float* c0_arr = theta_arr + (size_t)(N_BLK + 1) * D_DIM;
  float* c1_arr = c0_arr + (size_t)N_BLK * B_BLK;
  int* flags = (int*)(c1_arr + (size_t)N_BLK * B_BLK);

  cast_kernel<<<(N_STEPS * D_DIM / 8) / 256, 256, 0, stream>>>(
      xs, xb, theta_in, theta_arr, flags);
  gram_kernel<<<N_BLK * N_TILE, 256, 0, stream>>>(xb, G);
  solve_kernel<<<NWG, 256, 0, stream>>>(xb, G, theta_arr, c0_arr, c1_arr,
                                        flags, (float*)d_out);
}